// Round 3
// baseline (771.179 us; speedup 1.0000x reference)
//
#include <hip/hip_runtime.h>

// Problem constants (from reference): 16 clouds x 4096 pts, sample 1024, D=512
#define N_PER   4096
#define M_SAMP  1024
#define B_CL    16
#define D_FEAT  512
#define TPB     512
#define NWAVE   (TPB / 64)      // 8 waves -> 2 waves per SIMD (latency overlap)
#define PPT     (N_PER / TPB)   // 8 points per thread
#define NPAIR   (PPT / 2)       // 4 packed pairs per thread

typedef float v2f __attribute__((ext_vector_type(2)));

// ---------------------------------------------------------------------------
// u32 DPP max combine (value-only wave reduce). Lanes not supplied by the
// pattern combine with themselves (old == own value -> no-op).
// ---------------------------------------------------------------------------
template <int CTRL>
__device__ __forceinline__ unsigned dpp_maxu(unsigned v) {
    unsigned o = (unsigned)__builtin_amdgcn_update_dpp((int)v, (int)v, CTRL, 0xF, 0xF, false);
    return (o > v) ? o : v;
}

// ---------------------------------------------------------------------------
// FPS: one workgroup per cloud. TPB=512 => 8 waves = 2 waves/SIMD: per-SIMD
// VALU issue per step is unchanged (same 4096 pts/CU) but each wave's serial
// tail (DPP dep chain, LDS round-trips, readlane/ballot, barrier approach)
// overlaps with the sibling wave's work. R2 counters showed ~47% of active-
// SIMD time stalled with 1 wave/SIMD -- this attacks exactly that slack.
//
// Exactness (vs jnp reference, verified structure from the 549us kernel):
//  - distance math contract(off), same op order -> bit-exact d2 chain
//  - value-only in-loop max via v_max3_f32; first-occurrence index recovered
//    by descending equality scan (min j wins)
//  - wave reduce: 6-stage u32 DPP max on float bits (all dist >= 0)
//  - winner lane via readlane(63) -> ballot -> ctz (lane order == idx order)
//  - cross-wave merge via u64 keys (dist bits << 32 | (4095 - idx)):
//    max key == max dist, tie -> smaller global idx (jnp.argmax semantics)
// ---------------------------------------------------------------------------
__global__ __launch_bounds__(TPB)
__attribute__((amdgpu_waves_per_eu(2, 2)))
void fps_kernel(const float* __restrict__ pos, int* __restrict__ sidx) {
    __shared__ float4             spos[N_PER];     // 64 KiB coord table
    __shared__ unsigned long long sw[2][NWAVE];    // double-buffered wave keys
    __shared__ int                sloc[M_SAMP];    // sampled local indices

    const int cloud = blockIdx.x;
    const int tid   = threadIdx.x;
    const float* posb = pos + (size_t)cloud * N_PER * 3;

    // preload my 8 points (6 aligned float4 from global), pack into v2f regs,
    // and stage the same points into spos (one-time)
    v2f px2[NPAIR], py2[NPAIR], pz2[NPAIR], dist2[NPAIR];
    const int base = tid * PPT;
    {
        float f[24];
        const float4* posb4 = (const float4*)posb + tid * 6;
#pragma unroll
        for (int v = 0; v < 6; ++v) {
            float4 t = posb4[v];
            f[4 * v + 0] = t.x; f[4 * v + 1] = t.y;
            f[4 * v + 2] = t.z; f[4 * v + 3] = t.w;
        }
#pragma unroll
        for (int p = 0; p < NPAIR; ++p) {
            px2[p] = (v2f){f[6 * p + 0], f[6 * p + 3]};
            py2[p] = (v2f){f[6 * p + 1], f[6 * p + 4]};
            pz2[p] = (v2f){f[6 * p + 2], f[6 * p + 5]};
            dist2[p] = (v2f){1e30f, 1e30f};
        }
#pragma unroll
        for (int j = 0; j < PPT; ++j)
            spos[base + j] = make_float4(f[3 * j], f[3 * j + 1], f[3 * j + 2], 0.0f);
    }

    float lx = posb[0], ly = posb[1], lz = posb[2];   // start point = local 0
    if (tid == 0) sloc[0] = 0;

    const int wave = tid >> 6;
    const int lane = tid & 63;
    __syncthreads();   // spos visible

    for (int s = 1; s < M_SAMP; ++s) {
        float bv = -1.0f;     // all dist >= 0, so always beaten
        v2f lxv = {lx, lx}, lyv = {ly, ly}, lzv = {lz, lz};
#pragma unroll
        for (int p = 0; p < NPAIR; ++p) {
#pragma clang fp contract(off)
            v2f dx = px2[p] - lxv;
            v2f dy = py2[p] - lyv;
            v2f dz = pz2[p] - lzv;
            v2f d2 = dx * dx + dy * dy + dz * dz;          // contract off: exact jnp order
            v2f dn = __builtin_elementwise_min(dist2[p], d2);
            dist2[p] = dn;
            // value-only running max: one v_max3_f32 per pair
            asm("v_max3_f32 %0, %1, %2, %3" : "=v"(bv) : "v"(bv), "v"(dn.x), "v"(dn.y));
        }

        // first-occurrence j among my 8 slots: descending overwrite -> min j.
        // (independent of the DPP chain below; scheduler fills its bubbles)
        int bj = 0;
#pragma unroll
        for (int j = PPT - 1; j >= 0; --j) {
            float dj = (j & 1) ? dist2[j >> 1].y : dist2[j >> 1].x;
            bj = (dj == bv) ? j : bj;
        }

        // wave64 value max via u32 DPP (bv >= 0 -> float bits monotone)
        unsigned khi = __float_as_uint(bv);
        unsigned r = khi;
        r = dpp_maxu<0xB1>(r);     // quad_perm xor1
        r = dpp_maxu<0x4E>(r);     // quad_perm xor2
        r = dpp_maxu<0x141>(r);    // row_half_mirror
        r = dpp_maxu<0x140>(r);    // row_mirror
        r = dpp_maxu<0x142>(r);    // row_bcast15
        r = dpp_maxu<0x143>(r);    // row_bcast31  -> lane63 holds wave max

        unsigned smax = (unsigned)__builtin_amdgcn_readlane((int)r, 63);
        unsigned long long mask = __ballot(khi == smax);   // nonzero by construction
        int sl = __builtin_ctzll(mask);                    // first lane == lowest idx
        int widx_w = __builtin_amdgcn_readlane(base + bj, sl);  // wave winner idx

        const int buf = s & 1;
        if (lane == 0)
            sw[buf][wave] = ((unsigned long long)smax << 32) |
                            (unsigned)(N_PER - 1 - widx_w);   // tie -> min idx wins
        __syncthreads();   // only LDS outstanding -> cheap lgkm drain

        // cross-wave merge (broadcast b64 reads; keys unique -> exact winner)
        unsigned long long k = sw[buf][0];
#pragma unroll
        for (int w = 1; w < NWAVE; ++w) {
            unsigned long long k2 = sw[buf][w];
            if (k2 > k) k = k2;
        }
        int widx = N_PER - 1 - (int)(unsigned)(k & 0xFFFu);
        float4 wp = spos[widx];            // broadcast ds_read_b128
        lx = wp.x; ly = wp.y; lz = wp.z;
        if (tid == 0) sloc[s] = widx;      // LDS, drained at next barrier
    }

    // dump sampled indices to global once (coalesced)
    __syncthreads();
    for (int i = tid; i < M_SAMP; i += TPB)
        sidx[cloud * M_SAMP + i] = sloc[i];
}

// ---------------------------------------------------------------------------
// Gather x rows: out[r][:] = x[g][:], float4-vectorized. 16384 rows x 128 f4.
// sidx holds LOCAL per-cloud indices; globalize with cloud offset r/M*N_PER.
// ---------------------------------------------------------------------------
__global__ __launch_bounds__(256) void gather_x_kernel(const float4* __restrict__ x4,
                                                       const int* __restrict__ sidx,
                                                       float4* __restrict__ out4) {
    int id = blockIdx.x * 256 + threadIdx.x;     // 0 .. 16384*128-1
    int r  = id >> 7;                            // row in output
    int c  = id & 127;                           // float4 column
    int g  = sidx[r] + (r >> 10 << 12);          // + (r/1024)*4096 global offset
    out4[id] = x4[(size_t)g * (D_FEAT / 4) + c];
}

// ---------------------------------------------------------------------------
// Gather pos (3 f32/row) and batch (as float). 16384 threads.
// ---------------------------------------------------------------------------
__global__ __launch_bounds__(256) void gather_pb_kernel(const float* __restrict__ pos,
                                                        const int* __restrict__ batch,
                                                        const int* __restrict__ sidx,
                                                        float* __restrict__ out_pos,
                                                        float* __restrict__ out_batch) {
    int r = blockIdx.x * 256 + threadIdx.x;      // 0 .. 16383
    int g = sidx[r] + (r >> 10 << 12);
    out_pos[r * 3 + 0] = pos[g * 3 + 0];
    out_pos[r * 3 + 1] = pos[g * 3 + 1];
    out_pos[r * 3 + 2] = pos[g * 3 + 2];
    out_batch[r] = (float)batch[g];
}

extern "C" void kernel_launch(void* const* d_in, const int* in_sizes, int n_in,
                              void* d_out, int out_size, void* d_ws, size_t ws_size,
                              hipStream_t stream) {
    const float* x     = (const float*)d_in[0];   // [65536,512] f32
    const float* pos   = (const float*)d_in[1];   // [65536,3]   f32
    const int*   batch = (const int*)d_in[2];     // [65536]     i32

    int* sidx = (int*)d_ws;                       // [16384] local sampled indices

    float* out   = (float*)d_out;
    float* out_x = out;                                            // 16384*512
    float* out_p = out + (size_t)B_CL * M_SAMP * D_FEAT;           // 16384*3
    float* out_b = out_p + (size_t)B_CL * M_SAMP * 3;              // 16384

    // 1) FPS: 16 blocks (one per cloud), 512 threads (2 waves/SIMD)
    fps_kernel<<<B_CL, TPB, 0, stream>>>(pos, sidx);

    // 2) x gather: 16384 rows * 128 float4 / 256 threads = 8192 blocks
    gather_x_kernel<<<(B_CL * M_SAMP * (D_FEAT / 4)) / 256, 256, 0, stream>>>(
        (const float4*)x, sidx, (float4*)out_x);

    // 3) pos + batch gather: 16384 / 256 = 64 blocks
    gather_pb_kernel<<<(B_CL * M_SAMP) / 256, 256, 0, stream>>>(
        pos, batch, sidx, out_p, out_b);
}